// Round 2
// baseline (1804.623 us; speedup 1.0000x reference)
//
#include <hip/hip_runtime.h>
#include <hip/hip_bf16.h>
#include <math.h>

#define DIM 100
#define BN_EPS 1e-5f

// ---------------- degree count over both halves ----------------
// deg has 2*NE floats: [0,NE) = in-direction row degrees, [NE,2NE) = out-direction
__global__ void k_deg2(const int* __restrict__ ei, float* __restrict__ deg, int E, int NE) {
    int i = blockIdx.x * blockDim.x + threadIdx.x;
    int stride = gridDim.x * blockDim.x;
    int twoE = 2 * E;
    for (; i < twoE; i += stride) {
        int base = (i < E) ? 0 : NE;
        atomicAdd(&deg[base + ei[i]], 1.0f);
    }
}

__global__ void k_deginv(float* __restrict__ deg, int n) {
    int i = blockIdx.x * blockDim.x + threadIdx.x;
    if (i < n) { float d = deg[i]; deg[i] = d > 0.f ? rsqrtf(d) : 0.f; }
}

// ---------------- edge aggregation, float4, both halves fused ----------------
// thread handles (edge e, dims d..d+3). 25 threads per edge.
__global__ void k_agg(const int* __restrict__ ei, const int* __restrict__ et,
                      const float* __restrict__ x, const float* __restrict__ rel,
                      const float* __restrict__ dinv,  // 2*NE
                      float* __restrict__ agg_in, float* __restrict__ agg_out,
                      int E, int NE) {
    const int twoE = 2 * E;
    const int total = twoE * 25;
    int i = blockIdx.x * blockDim.x + threadIdx.x;
    int stride = gridDim.x * blockDim.x;
    for (; i < total; i += stride) {
        int e = i / 25;
        int d = (i - e * 25) * 4;
        int r = ei[e];
        int c = ei[twoE + e];
        int dbase = (e < E) ? 0 : NE;
        float norm = dinv[dbase + r] * dinv[dbase + c];
        if (norm != 0.f) {
            int t = et[e];
            float4 xv = *reinterpret_cast<const float4*>(x + c * DIM + d);
            float4 rv = *reinterpret_cast<const float4*>(rel + t * DIM + d);
            float* dst = ((e < E) ? agg_in : agg_out) + r * DIM + d;
            atomicAdd(dst + 0, xv.x * rv.x * norm);
            atomicAdd(dst + 1, xv.y * rv.y * norm);
            atomicAdd(dst + 2, xv.z * rv.z * norm);
            atomicAdd(dst + 3, xv.w * rv.w * norm);
        }
    }
}

// ---------------- tiled fused GEMM: v = [agg_in|agg_out|x.*loop_rel] @ [w_in;w_out;w_loop]
// BM=64 rows x BN=128 cols (100 valid), K=300, BK=12, 256 threads, 4x8 microtile.
// Fused column stats (sum, sumsq) into epilogue.
#define G_BM 64
#define G_BN 128
#define G_BK 12
#define G_NSTEP 25   // 300/12

__global__ __launch_bounds__(256) void k_gemm3(
    const float* __restrict__ agg_in, const float* __restrict__ agg_out,
    const float* __restrict__ x, const float* __restrict__ loop_rel,
    const float* __restrict__ w_in, const float* __restrict__ w_out,
    const float* __restrict__ w_loop,
    float* __restrict__ out, float* __restrict__ colsum, float* __restrict__ colsumsq,
    int NE)
{
    __shared__ float Ask[G_BK][G_BM + 4];   // k-major A tile (pad 4)
    __shared__ float Ws[G_BK][G_BN];
    __shared__ float csum[G_BN], csq[G_BN];

    int tid = threadIdx.x;
    if (tid < G_BN) { csum[tid] = 0.f; csq[tid] = 0.f; }

    int tm = tid & 15;    // row group: rows tm*4 .. tm*4+3
    int tn = tid >> 4;    // col group: cols tn*8 .. tn*8+7
    int row0 = blockIdx.x * G_BM;

    float acc[4][8];
#pragma unroll
    for (int r = 0; r < 4; ++r)
#pragma unroll
        for (int c = 0; c < 8; ++c) acc[r][c] = 0.f;

    for (int s = 0; s < G_NSTEP; ++s) {
        int k0 = s * G_BK;
        // stage A: 64*12 = 768 elems, 3 per thread (row-major global reads)
#pragma unroll
        for (int u = 0; u < 3; ++u) {
            int eidx = tid + u * 256;
            int rm = eidx / G_BK;
            int kk = eidx - rm * G_BK;
            int row = row0 + rm;
            int k = k0 + kk;
            float v = 0.f;
            if (row < NE) {
                if (k < DIM)            v = agg_in[row * DIM + k];
                else if (k < 2 * DIM)   v = agg_out[row * DIM + (k - DIM)];
                else                    v = x[row * DIM + (k - 2 * DIM)] * loop_rel[k - 2 * DIM];
            }
            Ask[kk][rm] = v;
        }
        // stage W: 12*128 = 1536 elems, 6 per thread
#pragma unroll
        for (int u = 0; u < 6; ++u) {
            int eidx = tid + u * 256;
            int kk = eidx >> 7;
            int c = eidx & 127;
            int k = k0 + kk;
            float v = 0.f;
            if (c < DIM) {
                if (k < DIM)            v = w_in[k * DIM + c];
                else if (k < 2 * DIM)   v = w_out[(k - DIM) * DIM + c];
                else                    v = w_loop[(k - 2 * DIM) * DIM + c];
            }
            Ws[kk][c] = v;
        }
        __syncthreads();
#pragma unroll
        for (int kk = 0; kk < G_BK; ++kk) {
            float4 av = *reinterpret_cast<const float4*>(&Ask[kk][tm * 4]);
            float4 w0 = *reinterpret_cast<const float4*>(&Ws[kk][tn * 8]);
            float4 w1 = *reinterpret_cast<const float4*>(&Ws[kk][tn * 8 + 4]);
            float a[4] = {av.x, av.y, av.z, av.w};
            float w[8] = {w0.x, w0.y, w0.z, w0.w, w1.x, w1.y, w1.z, w1.w};
#pragma unroll
            for (int r = 0; r < 4; ++r)
#pragma unroll
                for (int c = 0; c < 8; ++c) acc[r][c] += a[r] * w[c];
        }
        __syncthreads();
    }

    // ---- store + fused column stats ----
    int colb = tn * 8;
    float ps[8], pq[8];
#pragma unroll
    for (int c = 0; c < 8; ++c) {
        ps[c] = acc[0][c] + acc[1][c] + acc[2][c] + acc[3][c];
        pq[c] = acc[0][c] * acc[0][c] + acc[1][c] * acc[1][c]
              + acc[2][c] * acc[2][c] + acc[3][c] * acc[3][c];
    }
#pragma unroll
    for (int r = 0; r < 4; ++r) {
        int row = row0 + tm * 4 + r;
        if (row < NE) {
            if (colb <= 96) {
                float4 v0 = make_float4(acc[r][0], acc[r][1], acc[r][2], acc[r][3]);
                *reinterpret_cast<float4*>(&out[row * DIM + colb]) = v0;
            }
            if (colb + 4 <= 96) {
                float4 v1 = make_float4(acc[r][4], acc[r][5], acc[r][6], acc[r][7]);
                *reinterpret_cast<float4*>(&out[row * DIM + colb + 4]) = v1;
            }
        }
    }
#pragma unroll
    for (int c = 0; c < 8; ++c) {
        atomicAdd(&csum[colb + c], ps[c]);
        atomicAdd(&csq[colb + c], pq[c]);
    }
    __syncthreads();
    if (tid < DIM) {
        atomicAdd(&colsum[tid], csum[tid]);
        atomicAdd(&colsumsq[tid], csq[tid]);
    }
}

// stats of raw v -> affine S,T so that out = tanh(v*S[d] + T[d])
__global__ void k_finalize(const float* __restrict__ colsum, const float* __restrict__ colsumsq,
                           const float* __restrict__ gamma, const float* __restrict__ beta,
                           float* __restrict__ S, float* __restrict__ T, int NE) {
    int d = threadIdx.x;
    if (d < DIM) {
        float n = (float)NE;
        float mu = colsum[d] / n;
        float ex2 = colsumsq[d] / n;
        float var = ex2 - mu * mu;
        if (var < 0.f) var = 0.f;
        // ref: out_pre = v/3 + bias; BN removes bias, var scales by 1/9
        float s = rsqrtf(var * (1.0f / 9.0f) + BN_EPS) * (1.0f / 3.0f) * gamma[d];
        S[d] = s;
        T[d] = beta[d] - mu * s;
    }
}

// in-place BN+tanh, float4 (25 float4 per row exactly)
__global__ void k_bn_tanh4(float* __restrict__ v, const float* __restrict__ S,
                           const float* __restrict__ T, int total4) {
    int i = blockIdx.x * blockDim.x + threadIdx.x;
    if (i < total4) {
        int d = (i % 25) * 4;
        float4 val = reinterpret_cast<float4*>(v)[i];
        float4 s = *reinterpret_cast<const float4*>(S + d);
        float4 t = *reinterpret_cast<const float4*>(T + d);
        val.x = tanhf(val.x * s.x + t.x);
        val.y = tanhf(val.y * s.y + t.y);
        val.z = tanhf(val.z * s.z + t.z);
        val.w = tanhf(val.w * s.w + t.w);
        reinterpret_cast<float4*>(v)[i] = val;
    }
}

// rel_out = rel_embed @ w_rel, float4 over output dims
__global__ void k_relmm4(const float* __restrict__ rel, const float* __restrict__ w_rel,
                         float* __restrict__ out2, int total4) {
    int i = blockIdx.x * blockDim.x + threadIdx.x;
    if (i >= total4) return;
    int r = i / 25;
    int d = (i - r * 25) * 4;
    const float* a = rel + r * DIM;
    float4 acc = make_float4(0.f, 0.f, 0.f, 0.f);
#pragma unroll 4
    for (int k = 0; k < DIM; ++k) {
        float av = a[k];
        float4 w = *reinterpret_cast<const float4*>(w_rel + k * DIM + d);
        acc.x += av * w.x; acc.y += av * w.y; acc.z += av * w.z; acc.w += av * w.w;
    }
    *reinterpret_cast<float4*>(out2 + r * DIM + d) = acc;
}

extern "C" void kernel_launch(void* const* d_in, const int* in_sizes, int n_in,
                              void* d_out, int out_size, void* d_ws, size_t ws_size,
                              hipStream_t stream) {
    const float* x        = (const float*)d_in[0];
    const int*   ei       = (const int*)d_in[1];   // (2, 2E) row-major
    const int*   et       = (const int*)d_in[2];   // (2E,)
    const float* rel      = (const float*)d_in[3]; // (400,100)
    const float* w_in     = (const float*)d_in[4];
    const float* w_out    = (const float*)d_in[5];
    const float* w_loop   = (const float*)d_in[6];
    const float* w_rel    = (const float*)d_in[7];
    const float* loop_rel = (const float*)d_in[8];
    // d_in[9] = bias: cancels under BN
    const float* gamma    = (const float*)d_in[10];
    const float* beta     = (const float*)d_in[11];

    const int NE = in_sizes[0] / DIM;     // 50000
    const int E  = in_sizes[2] / 2;       // 500000

    float* out  = (float*)d_out;                 // (NE,DIM) tanh output
    float* out2 = out + (size_t)NE * DIM;        // (relRows,DIM) rel output
    const int relRows = in_sizes[3] / DIM;       // 400

    float* ws = (float*)d_ws;
    const size_t aggElems = (size_t)NE * DIM;
    const size_t needPrimary = (2 * aggElems + 2 * (size_t)NE + 512) * sizeof(float);

    const int B = 256;
    float* agg_in;
    float* agg_out;
    float* deg;

    if (ws_size >= needPrimary) {
        // two agg buffers in ws
        agg_in  = ws;
        agg_out = ws + aggElems;
        deg     = ws + 2 * aggElems;
        hipMemsetAsync(ws, 0, (2 * aggElems + 2 * (size_t)NE + 512) * sizeof(float), stream);
    } else {
        // alias agg_out onto d_out entity region (safe: each gemm block reads only
        // the A-rows it later writes, and writes after all its reads complete)
        agg_in  = ws;
        agg_out = out;
        deg     = ws + aggElems;
        hipMemsetAsync(ws, 0, (aggElems + 2 * (size_t)NE + 512) * sizeof(float), stream);
        hipMemsetAsync(out, 0, aggElems * sizeof(float), stream);
    }
    float* colsum   = deg + 2 * (size_t)NE;
    float* colsumsq = colsum + 128;
    float* Sv       = colsumsq + 128;
    float* Tv       = Sv + 128;

    k_deg2<<<2048, B, 0, stream>>>(ei, deg, E, NE);
    k_deginv<<<(2 * NE + B - 1) / B, B, 0, stream>>>(deg, 2 * NE);

    k_agg<<<8192, B, 0, stream>>>(ei, et, x, rel, deg, agg_in, agg_out, E, NE);

    k_gemm3<<<(NE + G_BM - 1) / G_BM, B, 0, stream>>>(agg_in, agg_out, x, loop_rel,
                                                      w_in, w_out, w_loop,
                                                      out, colsum, colsumsq, NE);

    k_finalize<<<1, 128, 0, stream>>>(colsum, colsumsq, gamma, beta, Sv, Tv, NE);

    int total4 = NE * (DIM / 4);
    k_bn_tanh4<<<(total4 + B - 1) / B, B, 0, stream>>>(out, Sv, Tv, total4);

    int rel4 = relRows * (DIM / 4);
    k_relmm4<<<(rel4 + B - 1) / B, B, 0, stream>>>(rel, w_rel, out2, rel4);
}

// Round 3
// 622.664 us; speedup vs baseline: 2.8982x; 2.8982x over previous
//
#include <hip/hip_runtime.h>
#include <hip/hip_bf16.h>
#include <math.h>

#define DIM 100
#define BN_EPS 1e-5f

// ============ phase 1: row-degree histogram (int atomics, L2-resident) ============
__global__ void k_hist(const int* __restrict__ ei, int* __restrict__ hist, int E, int NE) {
    int i = blockIdx.x * blockDim.x + threadIdx.x;
    int stride = gridDim.x * blockDim.x;
    int twoE = 2 * E;
    for (; i < twoE; i += stride) {
        int slot = ((i < E) ? 0 : NE) + ei[i];
        atomicAdd(&hist[slot], 1);
    }
}

// dinv[i] = count>0 ? rsqrt(count) : 0
__global__ void k_dinv(const int* __restrict__ hist, float* __restrict__ dinv, int n) {
    int i = blockIdx.x * blockDim.x + threadIdx.x;
    if (i < n) { int c = hist[i]; dinv[i] = c > 0 ? rsqrtf((float)c) : 0.f; }
}

// ============ phase 2: single-block exclusive scan -> base[0..n], cursor copy ============
__global__ void k_scan(const int* __restrict__ hist, int* __restrict__ base,
                       int* __restrict__ cursor, int n) {
    __shared__ int part[256];
    int tid = threadIdx.x;
    int chunk = (n + 255) / 256;
    int s0 = tid * chunk;
    int s1 = s0 + chunk; if (s1 > n) s1 = n;
    int sum = 0;
    for (int i = s0; i < s1; ++i) sum += hist[i];
    part[tid] = sum;
    __syncthreads();
    int val = sum;
    for (int off = 1; off < 256; off <<= 1) {
        int t = (tid >= off) ? part[tid - off] : 0;
        __syncthreads();
        part[tid] += t;
        __syncthreads();
    }
    int run = part[tid] - val;   // exclusive prefix of this chunk
    for (int i = s0; i < s1; ++i) {
        base[i] = run; cursor[i] = run;
        run += hist[i];
    }
    if (tid == 0) base[n] = part[255];
}

// ============ phase 3: scatter edges into CSR order ============
// packed[pos] = col | (type<<17)   (needs NE <= 131072, type < 32768)
__global__ void k_scatter(const int* __restrict__ ei, const int* __restrict__ et,
                          int* __restrict__ cursor, unsigned int* __restrict__ packed,
                          int E, int NE) {
    int i = blockIdx.x * blockDim.x + threadIdx.x;
    int stride = gridDim.x * blockDim.x;
    int twoE = 2 * E;
    for (; i < twoE; i += stride) {
        int r = ei[i];
        int c = ei[twoE + i];
        int t = et[i];
        int slot = ((i < E) ? 0 : NE) + r;
        int pos = atomicAdd(&cursor[slot], 1);
        packed[pos] = (unsigned int)c | ((unsigned int)t << 17);
    }
}

// ============ phase 4: per-row gather-aggregate, no atomics ============
// 25 threads per row (float4 each), 10 rows per 256-thread block.
__global__ __launch_bounds__(256) void k_agg_sorted(
    const unsigned int* __restrict__ packed, const int* __restrict__ base,
    const float* __restrict__ x, const float* __restrict__ rel,
    const float* __restrict__ dinv,
    float* __restrict__ agg_in, float* __restrict__ agg_out, int NE) {
    int tid = threadIdx.x;
    int rg = tid / 25;
    if (rg >= 10) return;
    int row = blockIdx.x * 10 + rg;
    int rmax = 2 * NE;
    if (row >= rmax) return;
    int d = (tid - rg * 25) * 4;
    int dbase = (row < NE) ? 0 : NE;
    float dr = dinv[row];
    int s = base[row], e = base[row + 1];
    float4 acc = make_float4(0.f, 0.f, 0.f, 0.f);
    for (int j = s; j < e; ++j) {
        unsigned int p = packed[j];
        int c = (int)(p & 0x1FFFFu);
        int t = (int)(p >> 17);
        float nrm = dr * dinv[dbase + c];
        float4 xv = *reinterpret_cast<const float4*>(x + c * DIM + d);
        float4 rv = *reinterpret_cast<const float4*>(rel + t * DIM + d);
        acc.x += xv.x * rv.x * nrm;
        acc.y += xv.y * rv.y * nrm;
        acc.z += xv.z * rv.z * nrm;
        acc.w += xv.w * rv.w * nrm;
    }
    float* dst = (row < NE) ? (agg_in + (size_t)row * DIM)
                            : (agg_out + (size_t)(row - NE) * DIM);
    *reinterpret_cast<float4*>(dst + d) = acc;
}

// ============ legacy atomic fallback (small-ws tier) ============
__global__ void k_agg_atomic(const int* __restrict__ ei, const int* __restrict__ et,
                             const float* __restrict__ x, const float* __restrict__ rel,
                             const float* __restrict__ dinv,
                             float* __restrict__ agg_in, float* __restrict__ agg_out,
                             int E, int NE) {
    const int twoE = 2 * E;
    const int total = twoE * 25;
    int i = blockIdx.x * blockDim.x + threadIdx.x;
    int stride = gridDim.x * blockDim.x;
    for (; i < total; i += stride) {
        int e = i / 25;
        int d = (i - e * 25) * 4;
        int r = ei[e];
        int c = ei[twoE + e];
        int dbase = (e < E) ? 0 : NE;
        float norm = dinv[dbase + r] * dinv[dbase + c];
        if (norm != 0.f) {
            int t = et[e];
            float4 xv = *reinterpret_cast<const float4*>(x + c * DIM + d);
            float4 rv = *reinterpret_cast<const float4*>(rel + t * DIM + d);
            float* dst = ((e < E) ? agg_in : agg_out) + r * DIM + d;
            atomicAdd(dst + 0, xv.x * rv.x * norm);
            atomicAdd(dst + 1, xv.y * rv.y * norm);
            atomicAdd(dst + 2, xv.z * rv.z * norm);
            atomicAdd(dst + 3, xv.w * rv.w * norm);
        }
    }
}

// ============ fused GEMM: v = [agg_in|agg_out|x.*loop_rel] @ [w_in;w_out;w_loop] ============
#define G_BM 64
#define G_BN 128
#define G_BK 12
#define G_NSTEP 25   // 300/12

__global__ __launch_bounds__(256) void k_gemm3(
    const float* __restrict__ agg_in, const float* __restrict__ agg_out,
    const float* __restrict__ x, const float* __restrict__ loop_rel,
    const float* __restrict__ w_in, const float* __restrict__ w_out,
    const float* __restrict__ w_loop,
    float* __restrict__ out, float* __restrict__ colsum, float* __restrict__ colsumsq,
    int NE)
{
    __shared__ float Ask[G_BK][G_BM + 4];
    __shared__ float Ws[G_BK][G_BN];
    __shared__ float csum[G_BN], csq[G_BN];

    int tid = threadIdx.x;
    if (tid < G_BN) { csum[tid] = 0.f; csq[tid] = 0.f; }

    int tm = tid & 15;
    int tn = tid >> 4;
    int row0 = blockIdx.x * G_BM;

    float acc[4][8];
#pragma unroll
    for (int r = 0; r < 4; ++r)
#pragma unroll
        for (int c = 0; c < 8; ++c) acc[r][c] = 0.f;

    for (int s = 0; s < G_NSTEP; ++s) {
        int k0 = s * G_BK;
#pragma unroll
        for (int u = 0; u < 3; ++u) {
            int eidx = tid + u * 256;
            int rm = eidx / G_BK;
            int kk = eidx - rm * G_BK;
            int row = row0 + rm;
            int k = k0 + kk;
            float v = 0.f;
            if (row < NE) {
                if (k < DIM)            v = agg_in[row * DIM + k];
                else if (k < 2 * DIM)   v = agg_out[row * DIM + (k - DIM)];
                else                    v = x[row * DIM + (k - 2 * DIM)] * loop_rel[k - 2 * DIM];
            }
            Ask[kk][rm] = v;
        }
#pragma unroll
        for (int u = 0; u < 6; ++u) {
            int eidx = tid + u * 256;
            int kk = eidx >> 7;
            int c = eidx & 127;
            int k = k0 + kk;
            float v = 0.f;
            if (c < DIM) {
                if (k < DIM)            v = w_in[k * DIM + c];
                else if (k < 2 * DIM)   v = w_out[(k - DIM) * DIM + c];
                else                    v = w_loop[(k - 2 * DIM) * DIM + c];
            }
            Ws[kk][c] = v;
        }
        __syncthreads();
#pragma unroll
        for (int kk = 0; kk < G_BK; ++kk) {
            float4 av = *reinterpret_cast<const float4*>(&Ask[kk][tm * 4]);
            float4 w0 = *reinterpret_cast<const float4*>(&Ws[kk][tn * 8]);
            float4 w1 = *reinterpret_cast<const float4*>(&Ws[kk][tn * 8 + 4]);
            float a[4] = {av.x, av.y, av.z, av.w};
            float w[8] = {w0.x, w0.y, w0.z, w0.w, w1.x, w1.y, w1.z, w1.w};
#pragma unroll
            for (int r = 0; r < 4; ++r)
#pragma unroll
                for (int c = 0; c < 8; ++c) acc[r][c] += a[r] * w[c];
        }
        __syncthreads();
    }

    int colb = tn * 8;
    float ps[8], pq[8];
#pragma unroll
    for (int c = 0; c < 8; ++c) {
        ps[c] = acc[0][c] + acc[1][c] + acc[2][c] + acc[3][c];
        pq[c] = acc[0][c] * acc[0][c] + acc[1][c] * acc[1][c]
              + acc[2][c] * acc[2][c] + acc[3][c] * acc[3][c];
    }
#pragma unroll
    for (int r = 0; r < 4; ++r) {
        int row = row0 + tm * 4 + r;
        if (row < NE) {
            if (colb <= 96) {
                float4 v0 = make_float4(acc[r][0], acc[r][1], acc[r][2], acc[r][3]);
                *reinterpret_cast<float4*>(&out[row * DIM + colb]) = v0;
            }
            if (colb + 4 <= 96) {
                float4 v1 = make_float4(acc[r][4], acc[r][5], acc[r][6], acc[r][7]);
                *reinterpret_cast<float4*>(&out[row * DIM + colb + 4]) = v1;
            }
        }
    }
#pragma unroll
    for (int c = 0; c < 8; ++c) {
        atomicAdd(&csum[colb + c], ps[c]);
        atomicAdd(&csq[colb + c], pq[c]);
    }
    __syncthreads();
    if (tid < DIM) {
        atomicAdd(&colsum[tid], csum[tid]);
        atomicAdd(&colsumsq[tid], csq[tid]);
    }
}

__global__ void k_finalize(const float* __restrict__ colsum, const float* __restrict__ colsumsq,
                           const float* __restrict__ gamma, const float* __restrict__ beta,
                           float* __restrict__ S, float* __restrict__ T, int NE) {
    int d = threadIdx.x;
    if (d < DIM) {
        float n = (float)NE;
        float mu = colsum[d] / n;
        float ex2 = colsumsq[d] / n;
        float var = ex2 - mu * mu;
        if (var < 0.f) var = 0.f;
        float s = rsqrtf(var * (1.0f / 9.0f) + BN_EPS) * (1.0f / 3.0f) * gamma[d];
        S[d] = s;
        T[d] = beta[d] - mu * s;
    }
}

__global__ void k_bn_tanh4(float* __restrict__ v, const float* __restrict__ S,
                           const float* __restrict__ T, int total4) {
    int i = blockIdx.x * blockDim.x + threadIdx.x;
    if (i < total4) {
        int d = (i % 25) * 4;
        float4 val = reinterpret_cast<float4*>(v)[i];
        float4 s = *reinterpret_cast<const float4*>(S + d);
        float4 t = *reinterpret_cast<const float4*>(T + d);
        val.x = tanhf(val.x * s.x + t.x);
        val.y = tanhf(val.y * s.y + t.y);
        val.z = tanhf(val.z * s.z + t.z);
        val.w = tanhf(val.w * s.w + t.w);
        reinterpret_cast<float4*>(v)[i] = val;
    }
}

__global__ void k_relmm4(const float* __restrict__ rel, const float* __restrict__ w_rel,
                         float* __restrict__ out2, int total4) {
    int i = blockIdx.x * blockDim.x + threadIdx.x;
    if (i >= total4) return;
    int r = i / 25;
    int d = (i - r * 25) * 4;
    const float* a = rel + r * DIM;
    float4 acc = make_float4(0.f, 0.f, 0.f, 0.f);
#pragma unroll 4
    for (int k = 0; k < DIM; ++k) {
        float av = a[k];
        float4 w = *reinterpret_cast<const float4*>(w_rel + k * DIM + d);
        acc.x += av * w.x; acc.y += av * w.y; acc.z += av * w.z; acc.w += av * w.w;
    }
    *reinterpret_cast<float4*>(out2 + r * DIM + d) = acc;
}

extern "C" void kernel_launch(void* const* d_in, const int* in_sizes, int n_in,
                              void* d_out, int out_size, void* d_ws, size_t ws_size,
                              hipStream_t stream) {
    const float* x        = (const float*)d_in[0];
    const int*   ei       = (const int*)d_in[1];   // (2, 2E)
    const int*   et       = (const int*)d_in[2];   // (2E,)
    const float* rel      = (const float*)d_in[3]; // (400,100)
    const float* w_in     = (const float*)d_in[4];
    const float* w_out    = (const float*)d_in[5];
    const float* w_loop   = (const float*)d_in[6];
    const float* w_rel    = (const float*)d_in[7];
    const float* loop_rel = (const float*)d_in[8];
    // d_in[9] = bias: cancels under BN
    const float* gamma    = (const float*)d_in[10];
    const float* beta     = (const float*)d_in[11];

    const int NE = in_sizes[0] / DIM;     // 50000
    const int E  = in_sizes[2] / 2;       // 500000

    float* out  = (float*)d_out;                 // (NE,DIM)
    float* out2 = out + (size_t)NE * DIM;        // (relRows,DIM)
    const int relRows = in_sizes[3] / DIM;       // 400

    const int B = 256;
    const size_t aggElems = (size_t)NE * DIM;
    const size_t twoNE = 2 * (size_t)NE;

    // ws layout (4-byte units):
    //   hist[2NE] | colstats[512] | dinv[2NE] | base[2NE+8] | cursor[2NE] | packed[2E] | agg[...]
    char* wsb = (char*)d_ws;
    int*   hist   = (int*)wsb;
    float* colsum = (float*)(hist + twoNE);
    float* colsumsq = colsum + 128;
    float* Sv     = colsumsq + 128;
    float* Tv     = Sv + 128;
    float* dinv   = Tv + 128;
    int*   base   = (int*)(dinv + twoNE);
    int*   cursor = base + twoNE + 8;
    unsigned int* packed = (unsigned int*)(cursor + twoNE);
    float* aggbuf = (float*)(packed + 2 * (size_t)E);

    const size_t fixedElems = twoNE + 512 + twoNE + (twoNE + 8) + twoNE + 2 * (size_t)E;
    const size_t needFull = (fixedElems + 2 * aggElems) * sizeof(float);
    const size_t needHalf = (fixedElems + aggElems) * sizeof(float);

    if (ws_size >= needHalf && NE <= 131072) {
        float* agg_in = aggbuf;
        float* agg_out = (ws_size >= needFull) ? (aggbuf + aggElems) : out;

        // zero: hist + colstats
        hipMemsetAsync(hist, 0, (twoNE + 512) * sizeof(float), stream);

        k_hist<<<1024, B, 0, stream>>>(ei, hist, E, NE);
        k_dinv<<<(int)((twoNE + B - 1) / B), B, 0, stream>>>(hist, dinv, (int)twoNE);
        k_scan<<<1, 256, 0, stream>>>(hist, base, cursor, (int)twoNE);
        k_scatter<<<1024, B, 0, stream>>>(ei, et, cursor, packed, E, NE);
        k_agg_sorted<<<(int)((twoNE + 9) / 10), B, 0, stream>>>(packed, base, x, rel, dinv,
                                                                agg_in, agg_out, NE);

        k_gemm3<<<(NE + G_BM - 1) / G_BM, B, 0, stream>>>(agg_in, agg_out, x, loop_rel,
                                                          w_in, w_out, w_loop,
                                                          out, colsum, colsumsq, NE);
    } else {
        // ---- atomic fallback: hist|colstats|dinv reuse; agg_in in ws after dinv ----
        float* agg_in = dinv + twoNE;
        float* agg_out = out;
        hipMemsetAsync(hist, 0, (twoNE + 512) * sizeof(float), stream);
        hipMemsetAsync(agg_in, 0, aggElems * sizeof(float), stream);
        hipMemsetAsync(out, 0, aggElems * sizeof(float), stream);

        k_hist<<<1024, B, 0, stream>>>(ei, hist, E, NE);
        k_dinv<<<(int)((twoNE + B - 1) / B), B, 0, stream>>>(hist, dinv, (int)twoNE);
        k_agg_atomic<<<8192, B, 0, stream>>>(ei, et, x, rel, dinv, agg_in, agg_out, E, NE);

        k_gemm3<<<(NE + G_BM - 1) / G_BM, B, 0, stream>>>(agg_in, agg_out, x, loop_rel,
                                                          w_in, w_out, w_loop,
                                                          out, colsum, colsumsq, NE);
    }

    k_finalize<<<1, 128, 0, stream>>>(colsum, colsumsq, gamma, beta, Sv, Tv, NE);

    int total4 = NE * (DIM / 4);
    k_bn_tanh4<<<(total4 + B - 1) / B, B, 0, stream>>>(out, Sv, Tv, total4);

    int rel4 = relRows * (DIM / 4);
    k_relmm4<<<(rel4 + B - 1) / B, B, 0, stream>>>(rel, w_rel, out2, rel4);
}

// Round 4
// 253.547 us; speedup vs baseline: 7.1175x; 2.4558x over previous
//
#include <hip/hip_runtime.h>
#include <hip/hip_bf16.h>
#include <math.h>

#define DIM 100
#define BN_EPS 1e-5f

using short8v = __attribute__((ext_vector_type(8))) short;
using f32x4v  = __attribute__((ext_vector_type(4))) float;

__device__ __forceinline__ short f2bf(float f) {
    unsigned u = __float_as_uint(f);
    unsigned r = (u + 0x7fffu + ((u >> 16) & 1u)) >> 16;
    return (short)r;
}

// ============ phase 1: row-degree histogram ============
__global__ void k_hist(const int* __restrict__ ei, int* __restrict__ hist, int E, int NE) {
    int i = blockIdx.x * blockDim.x + threadIdx.x;
    int stride = gridDim.x * blockDim.x;
    int twoE = 2 * E;
    for (; i < twoE; i += stride) {
        int slot = ((i < E) ? 0 : NE) + ei[i];
        atomicAdd(&hist[slot], 1);
    }
}

__global__ void k_dinv(const int* __restrict__ hist, float* __restrict__ dinv, int n) {
    int i = blockIdx.x * blockDim.x + threadIdx.x;
    if (i < n) { int c = hist[i]; dinv[i] = c > 0 ? rsqrtf((float)c) : 0.f; }
}

// ============ phase 2: parallel exclusive scan (3 kernels) ============
__global__ void k_scanA(const int* __restrict__ hist, int* __restrict__ base,
                        int* __restrict__ blocksum, int n) {
    __shared__ int lsum[256];
    int tid = threadIdx.x;
    int i0 = blockIdx.x * 1024 + tid * 4;
    int v0 = (i0 + 0 < n) ? hist[i0 + 0] : 0;
    int v1 = (i0 + 1 < n) ? hist[i0 + 1] : 0;
    int v2 = (i0 + 2 < n) ? hist[i0 + 2] : 0;
    int v3 = (i0 + 3 < n) ? hist[i0 + 3] : 0;
    int s = v0 + v1 + v2 + v3;
    lsum[tid] = s;
    __syncthreads();
    for (int off = 1; off < 256; off <<= 1) {
        int t = (tid >= off) ? lsum[tid - off] : 0;
        __syncthreads();
        lsum[tid] += t;
        __syncthreads();
    }
    int excl = lsum[tid] - s;
    if (i0 + 0 < n) base[i0 + 0] = excl;
    if (i0 + 1 < n) base[i0 + 1] = excl + v0;
    if (i0 + 2 < n) base[i0 + 2] = excl + v0 + v1;
    if (i0 + 3 < n) base[i0 + 3] = excl + v0 + v1 + v2;
    if (tid == 255) blocksum[blockIdx.x] = lsum[255];
}

__global__ void k_scanB(const int* __restrict__ blocksum, int* __restrict__ blockoff, int nb) {
    __shared__ int s[128];
    int tid = threadIdx.x;
    int v = (tid < nb) ? blocksum[tid] : 0;
    s[tid] = v;
    __syncthreads();
    for (int off = 1; off < 128; off <<= 1) {
        int t = (tid >= off) ? s[tid - off] : 0;
        __syncthreads();
        s[tid] += t;
        __syncthreads();
    }
    if (tid < nb) blockoff[tid] = s[tid] - v;
}

__global__ void k_scanC(int* __restrict__ base, int* __restrict__ cursor,
                        const int* __restrict__ blockoff, int n, int total) {
    int i0 = blockIdx.x * 1024 + threadIdx.x * 4;
    int off = blockoff[blockIdx.x];
#pragma unroll
    for (int j = 0; j < 4; ++j) {
        int i = i0 + j;
        if (i < n) { int v = base[i] + off; base[i] = v; cursor[i] = v; }
    }
    if (blockIdx.x == 0 && threadIdx.x == 0) base[n] = total;
}

// ============ phase 3: scatter edges into CSR order ============
__global__ void k_scatter(const int* __restrict__ ei, const int* __restrict__ et,
                          int* __restrict__ cursor, unsigned int* __restrict__ packed,
                          int E, int NE) {
    int i = blockIdx.x * blockDim.x + threadIdx.x;
    int stride = gridDim.x * blockDim.x;
    int twoE = 2 * E;
    for (; i < twoE; i += stride) {
        int r = ei[i];
        int c = ei[twoE + i];
        int t = et[i];
        int slot = ((i < E) ? 0 : NE) + r;
        int pos = atomicAdd(&cursor[slot], 1);
        packed[pos] = (unsigned int)c | ((unsigned int)t << 17);
    }
}

// ============ phase 4: per-row gather-aggregate, no atomics ============
__global__ __launch_bounds__(256) void k_agg_sorted(
    const unsigned int* __restrict__ packed, const int* __restrict__ base,
    const float* __restrict__ x, const float* __restrict__ rel,
    const float* __restrict__ dinv,
    float* __restrict__ agg_in, float* agg_out, int NE) {
    int tid = threadIdx.x;
    int rg = tid / 25;
    if (rg >= 10) return;
    int row = blockIdx.x * 10 + rg;
    int rmax = 2 * NE;
    if (row >= rmax) return;
    int d = (tid - rg * 25) * 4;
    int dbase = (row < NE) ? 0 : NE;
    float dr = dinv[row];
    int s = base[row], e = base[row + 1];
    float4 acc = make_float4(0.f, 0.f, 0.f, 0.f);
    for (int j = s; j < e; ++j) {
        unsigned int p = packed[j];
        int c = (int)(p & 0x1FFFFu);
        int t = (int)(p >> 17);
        float nrm = dr * dinv[dbase + c];
        float4 xv = *reinterpret_cast<const float4*>(x + c * DIM + d);
        float4 rv = *reinterpret_cast<const float4*>(rel + t * DIM + d);
        acc.x += xv.x * rv.x * nrm;
        acc.y += xv.y * rv.y * nrm;
        acc.z += xv.z * rv.z * nrm;
        acc.w += xv.w * rv.w * nrm;
    }
    float* dst = (row < NE) ? (agg_in + (size_t)row * DIM)
                            : (agg_out + (size_t)(row - NE) * DIM);
    *reinterpret_cast<float4*>(dst + d) = acc;
}

// ============ atomic fallback (small-ws tier) ============
__global__ void k_agg_atomic(const int* __restrict__ ei, const int* __restrict__ et,
                             const float* __restrict__ x, const float* __restrict__ rel,
                             const float* __restrict__ dinv,
                             float* agg_in, float* agg_out, int E, int NE) {
    const int twoE = 2 * E;
    const int total = twoE * 25;
    int i = blockIdx.x * blockDim.x + threadIdx.x;
    int stride = gridDim.x * blockDim.x;
    for (; i < total; i += stride) {
        int e = i / 25;
        int d = (i - e * 25) * 4;
        int r = ei[e];
        int c = ei[twoE + e];
        int dbase = (e < E) ? 0 : NE;
        float norm = dinv[dbase + r] * dinv[dbase + c];
        if (norm != 0.f) {
            int t = et[e];
            float4 xv = *reinterpret_cast<const float4*>(x + c * DIM + d);
            float4 rv = *reinterpret_cast<const float4*>(rel + t * DIM + d);
            float* dst = ((e < E) ? agg_in : agg_out) + r * DIM + d;
            atomicAdd(dst + 0, xv.x * rv.x * norm);
            atomicAdd(dst + 1, xv.y * rv.y * norm);
            atomicAdd(dst + 2, xv.z * rv.z * norm);
            atomicAdd(dst + 3, xv.w * rv.w * norm);
        }
    }
}

// ============ W fragment pre-pack ============
// wfrag[((src*4+ks)*7+nt)*64 + lane] = 8 bf16:
//   element j = W_src[ks*32 + (lane>>4)*8 + j][nt*16 + (lane&15)], 0 if OOB.
__global__ void k_wprep(const float* __restrict__ w_in, const float* __restrict__ w_out,
                        const float* __restrict__ w_loop, short* __restrict__ wfrag) {
    int g = blockIdx.x * blockDim.x + threadIdx.x;
    if (g >= 3 * 4 * 7 * 64) return;
    int lane = g & 63;
    int rest = g >> 6;
    int nt = rest % 7;
    int ks = (rest / 7) % 4;
    int src = rest / 28;
    const float* W = (src == 0) ? w_in : (src == 1) ? w_out : w_loop;
    int col = nt * 16 + (lane & 15);
    short8v frag;
#pragma unroll
    for (int j = 0; j < 8; ++j) {
        int k = ks * 32 + ((lane >> 4) << 3) + j;
        float v = (k < DIM && col < DIM) ? W[k * DIM + col] : 0.f;
        frag[j] = f2bf(v);
    }
    reinterpret_cast<short8v*>(wfrag)[g] = frag;
}

// ============ MFMA GEMM: out = [agg_in|agg_out|x.*loop_rel] @ [w_in;w_out;w_loop] ============
// One wave per 16 rows. K = 3 sources x 4 ksteps of 32 (tail masked). N = 7 tiles (112, 100 valid).
__global__ __launch_bounds__(256) void k_gemm_mfma(
    const float* __restrict__ agg_in, const float* agg_out,
    const float* __restrict__ x, const float* __restrict__ loop_rel,
    const short* __restrict__ wfrag, float* out, int NE) {
    int w = blockIdx.x * 4 + (threadIdx.x >> 6);
    if (w * 16 >= NE) return;
    int lane = threadIdx.x & 63;
    int row = w * 16 + (lane & 15);
    int kg = lane >> 4;     // 0..3

    f32x4v acc[7];
#pragma unroll
    for (int nt = 0; nt < 7; ++nt) acc[nt] = (f32x4v){0.f, 0.f, 0.f, 0.f};

    for (int src = 0; src < 3; ++src) {
        const float* A = (src == 0) ? agg_in : (src == 1) ? agg_out : x;
        const float* Arow = A + (size_t)row * DIM;
#pragma unroll
        for (int ks = 0; ks < 4; ++ks) {
            int k0 = ks * 32 + kg * 8;
            short8v af = (short8v){0, 0, 0, 0, 0, 0, 0, 0};
            if (ks < 3) {
                float4 lo = *reinterpret_cast<const float4*>(Arow + k0);
                float4 hi = *reinterpret_cast<const float4*>(Arow + k0 + 4);
                float v[8] = {lo.x, lo.y, lo.z, lo.w, hi.x, hi.y, hi.z, hi.w};
                if (src == 2) {
                    float4 l0 = *reinterpret_cast<const float4*>(loop_rel + k0);
                    float4 l1 = *reinterpret_cast<const float4*>(loop_rel + k0 + 4);
                    v[0] *= l0.x; v[1] *= l0.y; v[2] *= l0.z; v[3] *= l0.w;
                    v[4] *= l1.x; v[5] *= l1.y; v[6] *= l1.z; v[7] *= l1.w;
                }
#pragma unroll
                for (int j = 0; j < 8; ++j) af[j] = f2bf(v[j]);
            } else if (kg == 0) {
                // tail: k = 96..99 valid only (lane group 0, j<4)
                float4 lo = *reinterpret_cast<const float4*>(Arow + 96);
                float v[4] = {lo.x, lo.y, lo.z, lo.w};
                if (src == 2) {
                    float4 l0 = *reinterpret_cast<const float4*>(loop_rel + 96);
                    v[0] *= l0.x; v[1] *= l0.y; v[2] *= l0.z; v[3] *= l0.w;
                }
#pragma unroll
                for (int j = 0; j < 4; ++j) af[j] = f2bf(v[j]);
            }
            int fb = ((src * 4 + ks) * 7) * 64 + lane;
#pragma unroll
            for (int nt = 0; nt < 7; ++nt) {
                short8v bf = reinterpret_cast<const short8v*>(wfrag)[fb + nt * 64];
                acc[nt] = __builtin_amdgcn_mfma_f32_16x16x32_bf16(af, bf, acc[nt], 0, 0, 0);
            }
        }
    }

    // epilogue: C row = w*16 + kg*4 + r, col = nt*16 + (lane&15)
    int cbase = lane & 15;
#pragma unroll
    for (int nt = 0; nt < 7; ++nt) {
        int col = nt * 16 + cbase;
        if (col < DIM) {
#pragma unroll
            for (int r = 0; r < 4; ++r) {
                int orow = w * 16 + kg * 4 + r;
                out[(size_t)orow * DIM + col] = acc[nt][r];
            }
        }
    }
}

// ============ column stats (vectorized streams + LDS reduce) ============
// grid*block must be a multiple of 25: 250 blocks x 256 = 64000 -> 2560 row-streams
__global__ __launch_bounds__(256) void k_stats2(const float* __restrict__ v,
                                                float* __restrict__ colsum,
                                                float* __restrict__ colsumsq, int NE) {
    __shared__ float s[DIM], q[DIM];
    int tid = threadIdx.x;
    if (tid < DIM) { s[tid] = 0.f; q[tid] = 0.f; }
    __syncthreads();
    int g = blockIdx.x * blockDim.x + tid;
    int c4 = (g % 25) * 4;
    int row = g / 25;
    const int rstride = 2560;
    float4 ss = make_float4(0.f, 0.f, 0.f, 0.f);
    float4 qq = make_float4(0.f, 0.f, 0.f, 0.f);
    for (; row < NE; row += rstride) {
        float4 val = *reinterpret_cast<const float4*>(v + (size_t)row * DIM + c4);
        ss.x += val.x; ss.y += val.y; ss.z += val.z; ss.w += val.w;
        qq.x += val.x * val.x; qq.y += val.y * val.y;
        qq.z += val.z * val.z; qq.w += val.w * val.w;
    }
    atomicAdd(&s[c4 + 0], ss.x); atomicAdd(&s[c4 + 1], ss.y);
    atomicAdd(&s[c4 + 2], ss.z); atomicAdd(&s[c4 + 3], ss.w);
    atomicAdd(&q[c4 + 0], qq.x); atomicAdd(&q[c4 + 1], qq.y);
    atomicAdd(&q[c4 + 2], qq.z); atomicAdd(&q[c4 + 3], qq.w);
    __syncthreads();
    if (tid < DIM) {
        atomicAdd(&colsum[tid], s[tid]);
        atomicAdd(&colsumsq[tid], q[tid]);
    }
}

__global__ void k_finalize(const float* __restrict__ colsum, const float* __restrict__ colsumsq,
                           const float* __restrict__ gamma, const float* __restrict__ beta,
                           float* __restrict__ S, float* __restrict__ T, int NE) {
    int d = threadIdx.x;
    if (d < DIM) {
        float n = (float)NE;
        float mu = colsum[d] / n;
        float ex2 = colsumsq[d] / n;
        float var = ex2 - mu * mu;
        if (var < 0.f) var = 0.f;
        float s = rsqrtf(var * (1.0f / 9.0f) + BN_EPS) * (1.0f / 3.0f) * gamma[d];
        S[d] = s;
        T[d] = beta[d] - mu * s;
    }
}

__global__ void k_bn_tanh4(float* __restrict__ v, const float* __restrict__ S,
                           const float* __restrict__ T, int total4) {
    int i = blockIdx.x * blockDim.x + threadIdx.x;
    if (i < total4) {
        int d = (i % 25) * 4;
        float4 val = reinterpret_cast<float4*>(v)[i];
        float4 s = *reinterpret_cast<const float4*>(S + d);
        float4 t = *reinterpret_cast<const float4*>(T + d);
        val.x = tanhf(val.x * s.x + t.x);
        val.y = tanhf(val.y * s.y + t.y);
        val.z = tanhf(val.z * s.z + t.z);
        val.w = tanhf(val.w * s.w + t.w);
        reinterpret_cast<float4*>(v)[i] = val;
    }
}

__global__ void k_relmm4(const float* __restrict__ rel, const float* __restrict__ w_rel,
                         float* __restrict__ out2, int total4) {
    int i = blockIdx.x * blockDim.x + threadIdx.x;
    if (i >= total4) return;
    int r = i / 25;
    int d = (i - r * 25) * 4;
    const float* a = rel + r * DIM;
    float4 acc = make_float4(0.f, 0.f, 0.f, 0.f);
#pragma unroll 4
    for (int k = 0; k < DIM; ++k) {
        float av = a[k];
        float4 w = *reinterpret_cast<const float4*>(w_rel + k * DIM + d);
        acc.x += av * w.x; acc.y += av * w.y; acc.z += av * w.z; acc.w += av * w.w;
    }
    *reinterpret_cast<float4*>(out2 + r * DIM + d) = acc;
}

extern "C" void kernel_launch(void* const* d_in, const int* in_sizes, int n_in,
                              void* d_out, int out_size, void* d_ws, size_t ws_size,
                              hipStream_t stream) {
    const float* x        = (const float*)d_in[0];
    const int*   ei       = (const int*)d_in[1];
    const int*   et       = (const int*)d_in[2];
    const float* rel      = (const float*)d_in[3];
    const float* w_in     = (const float*)d_in[4];
    const float* w_out    = (const float*)d_in[5];
    const float* w_loop   = (const float*)d_in[6];
    const float* w_rel    = (const float*)d_in[7];
    const float* loop_rel = (const float*)d_in[8];
    const float* gamma    = (const float*)d_in[10];
    const float* beta     = (const float*)d_in[11];

    const int NE = in_sizes[0] / DIM;     // 50000
    const int E  = in_sizes[2] / 2;       // 500000

    float* out  = (float*)d_out;
    float* out2 = out + (size_t)NE * DIM;
    const int relRows = in_sizes[3] / DIM;

    const int B = 256;
    const size_t aggElems = (size_t)NE * DIM;
    const size_t twoNE = 2 * (size_t)NE;
    const int n = (int)twoNE;
    const int nb = (n + 1023) / 1024;     // scan blocks (98)
    const int WFRAG_SHORTS = 3 * 4 * 7 * 64 * 8;   // 43008
    const int WFRAG_INTS = WFRAG_SHORTS / 2;       // 21504

    // ws layout (ints):
    // hist[2NE] | colsum[128] colsumsq[128] Sv[128] Tv[128] | blocksum[128] blockoff[128]
    // | dinv[2NE] | base[2NE+16] | cursor[2NE] | wfrag[21504] | packed[2E] | agg_in[NE*DIM]
    int* wsI = (int*)d_ws;
    int*   hist     = wsI;
    float* colsum   = (float*)(hist + twoNE);
    float* colsumsq = colsum + 128;
    float* Sv       = colsumsq + 128;
    float* Tv       = Sv + 128;
    int*   blocksum = (int*)(Tv + 128);
    int*   blockoff = blocksum + 128;

    const size_t needSorted = (twoNE + 512 + 256 + twoNE + (twoNE + 16) + twoNE
                               + WFRAG_INTS + 2 * (size_t)E + aggElems) * 4;
    const size_t needAtomic = (twoNE + 512 + 256 + twoNE + aggElems + WFRAG_INTS) * 4;

    if (ws_size >= needSorted && NE <= 131072) {
        float* dinv   = (float*)(blockoff + 128);
        int*   base   = (int*)(dinv + twoNE);
        int*   cursor = base + twoNE + 16;
        short* wfrag  = (short*)(cursor + twoNE);
        unsigned int* packed = (unsigned int*)(cursor + twoNE + WFRAG_INTS);
        float* agg_in = (float*)(packed + 2 * (size_t)E);
        float* agg_out = out;   // alias: safe, each gemm wave reads only its own rows

        hipMemsetAsync(hist, 0, (twoNE + 512 + 256) * 4, stream);

        k_hist<<<1024, B, 0, stream>>>(ei, hist, E, NE);
        k_dinv<<<(n + B - 1) / B, B, 0, stream>>>(hist, (float*)dinv, n);
        k_scanA<<<nb, B, 0, stream>>>(hist, base, blocksum, n);
        k_scanB<<<1, 128, 0, stream>>>(blocksum, blockoff, nb);
        k_scanC<<<nb, B, 0, stream>>>(base, cursor, blockoff, n, 2 * E);
        k_scatter<<<1024, B, 0, stream>>>(ei, et, cursor, packed, E, NE);
        k_wprep<<<(3 * 4 * 7 * 64 + B - 1) / B, B, 0, stream>>>(w_in, w_out, w_loop, wfrag);
        k_agg_sorted<<<(n + 9) / 10, B, 0, stream>>>(packed, base, x, rel, dinv,
                                                     agg_in, agg_out, NE);
        k_gemm_mfma<<<(NE / 16 + 3) / 4, B, 0, stream>>>(agg_in, agg_out, x, loop_rel,
                                                         wfrag, out, NE);
    } else {
        // atomic fallback
        float* dinv   = (float*)(blockoff + 128);
        float* agg_in = dinv + twoNE;
        short* wfrag  = (short*)(agg_in + aggElems);
        float* agg_out = out;

        hipMemsetAsync(hist, 0, (twoNE + 512 + 256) * 4, stream);
        hipMemsetAsync(agg_in, 0, aggElems * 4, stream);
        hipMemsetAsync(out, 0, aggElems * 4, stream);

        k_hist<<<1024, B, 0, stream>>>(ei, hist, E, NE);
        k_dinv<<<(n + B - 1) / B, B, 0, stream>>>(hist, dinv, n);
        k_wprep<<<(3 * 4 * 7 * 64 + B - 1) / B, B, 0, stream>>>(w_in, w_out, w_loop, wfrag);
        k_agg_atomic<<<8192, B, 0, stream>>>(ei, et, x, rel, dinv, agg_in, agg_out, E, NE);
        k_gemm_mfma<<<(NE / 16 + 3) / 4, B, 0, stream>>>(agg_in, agg_out, x, loop_rel,
                                                         wfrag, out, NE);
    }

    k_stats2<<<250, B, 0, stream>>>(out, colsum, colsumsq, NE);
    k_finalize<<<1, 128, 0, stream>>>(colsum, colsumsq, gamma, beta, Sv, Tv, NE);

    int total4 = NE * (DIM / 4);
    k_bn_tanh4<<<(total4 + B - 1) / B, B, 0, stream>>>(out, Sv, Tv, total4);

    int rel4 = relRows * (DIM / 4);
    k_relmm4<<<(rel4 + B - 1) / B, B, 0, stream>>>(rel, w_rel, out2, rel4);
}

// Round 5
// 252.209 us; speedup vs baseline: 7.1553x; 1.0053x over previous
//
#include <hip/hip_runtime.h>
#include <hip/hip_bf16.h>
#include <math.h>

#define DIM 100
#define BN_EPS 1e-5f

using short8v = __attribute__((ext_vector_type(8))) short;
using f32x4v  = __attribute__((ext_vector_type(4))) float;

__device__ __forceinline__ short f2bf(float f) {
    unsigned u = __float_as_uint(f);
    unsigned r = (u + 0x7fffu + ((u >> 16) & 1u)) >> 16;
    return (short)r;
}

// ============ phase 1: row-degree histogram ============
__global__ void k_hist(const int* __restrict__ ei, int* __restrict__ hist, int E, int NE) {
    int i = blockIdx.x * blockDim.x + threadIdx.x;
    int stride = gridDim.x * blockDim.x;
    int twoE = 2 * E;
    for (; i < twoE; i += stride) {
        int slot = ((i < E) ? 0 : NE) + ei[i];
        atomicAdd(&hist[slot], 1);
    }
}

// standalone dinv (fallback path only)
__global__ void k_dinv(const int* __restrict__ hist, float* __restrict__ dinv, int n) {
    int i = blockIdx.x * blockDim.x + threadIdx.x;
    if (i < n) { int c = hist[i]; dinv[i] = c > 0 ? rsqrtf((float)c) : 0.f; }
}

// ============ phase 2: parallel exclusive scan (+ dinv fused) ============
__global__ void k_scanA(const int* __restrict__ hist, int* __restrict__ base,
                        int* __restrict__ blocksum, float* __restrict__ dinv, int n) {
    __shared__ int lsum[256];
    int tid = threadIdx.x;
    int i0 = blockIdx.x * 1024 + tid * 4;
    int v0 = (i0 + 0 < n) ? hist[i0 + 0] : 0;
    int v1 = (i0 + 1 < n) ? hist[i0 + 1] : 0;
    int v2 = (i0 + 2 < n) ? hist[i0 + 2] : 0;
    int v3 = (i0 + 3 < n) ? hist[i0 + 3] : 0;
    if (i0 + 0 < n) dinv[i0 + 0] = v0 > 0 ? rsqrtf((float)v0) : 0.f;
    if (i0 + 1 < n) dinv[i0 + 1] = v1 > 0 ? rsqrtf((float)v1) : 0.f;
    if (i0 + 2 < n) dinv[i0 + 2] = v2 > 0 ? rsqrtf((float)v2) : 0.f;
    if (i0 + 3 < n) dinv[i0 + 3] = v3 > 0 ? rsqrtf((float)v3) : 0.f;
    int s = v0 + v1 + v2 + v3;
    lsum[tid] = s;
    __syncthreads();
    for (int off = 1; off < 256; off <<= 1) {
        int t = (tid >= off) ? lsum[tid - off] : 0;
        __syncthreads();
        lsum[tid] += t;
        __syncthreads();
    }
    int excl = lsum[tid] - s;
    if (i0 + 0 < n) base[i0 + 0] = excl;
    if (i0 + 1 < n) base[i0 + 1] = excl + v0;
    if (i0 + 2 < n) base[i0 + 2] = excl + v0 + v1;
    if (i0 + 3 < n) base[i0 + 3] = excl + v0 + v1 + v2;
    if (tid == 255) blocksum[blockIdx.x] = lsum[255];
}

__global__ void k_scanB(const int* __restrict__ blocksum, int* __restrict__ blockoff, int nb) {
    __shared__ int s[256];
    int tid = threadIdx.x;
    int v = (tid < nb) ? blocksum[tid] : 0;
    s[tid] = v;
    __syncthreads();
    for (int off = 1; off < 256; off <<= 1) {
        int t = (tid >= off) ? s[tid - off] : 0;
        __syncthreads();
        s[tid] += t;
        __syncthreads();
    }
    if (tid < nb) blockoff[tid] = s[tid] - v;
}

__global__ void k_scanC(int* __restrict__ base, int* __restrict__ cursor,
                        const int* __restrict__ blockoff, int n, int total) {
    int i0 = blockIdx.x * 1024 + threadIdx.x * 4;
    int off = blockoff[blockIdx.x];
#pragma unroll
    for (int j = 0; j < 4; ++j) {
        int i = i0 + j;
        if (i < n) { int v = base[i] + off; base[i] = v; cursor[i] = v; }
    }
    if (blockIdx.x == 0 && threadIdx.x == 0) base[n] = total;
}

// ============ phase 3: scatter edges into CSR order ============
__global__ void k_scatter(const int* __restrict__ ei, const int* __restrict__ et,
                          int* __restrict__ cursor, unsigned int* __restrict__ packed,
                          int E, int NE) {
    int i = blockIdx.x * blockDim.x + threadIdx.x;
    int stride = gridDim.x * blockDim.x;
    int twoE = 2 * E;
    for (; i < twoE; i += stride) {
        int r = ei[i];
        int c = ei[twoE + i];
        int t = et[i];
        int slot = ((i < E) ? 0 : NE) + r;
        int pos = atomicAdd(&cursor[slot], 1);
        packed[pos] = (unsigned int)c | ((unsigned int)t << 17);
    }
}

// ============ phase 4: gather-aggregate, one row per wave, 4 edges in flight ============
__global__ __launch_bounds__(256) void k_agg2(
    const unsigned int* __restrict__ packed, const int* __restrict__ base,
    const float* __restrict__ x, const float* __restrict__ rel,
    const float* __restrict__ dinv,
    float* __restrict__ agg_in, float* agg_out, int NE) {
    int tid = threadIdx.x;
    int row = blockIdx.x * 4 + (tid >> 6);
    if (row >= 2 * NE) return;             // wave-uniform exit, no barriers in kernel
    int lane = tid & 63;
    int sub = lane >> 5;                   // 0: even edges, 1: odd edges
    int slot = lane & 31;
    int d = (slot < 25) ? slot * 4 : 96;   // inactive lanes clamp (harmless dup loads)
    int dbase = (row < NE) ? 0 : NE;
    float dr = dinv[row];
    int s = base[row], e = base[row + 1];

    float4 acc0 = make_float4(0.f, 0.f, 0.f, 0.f);
    float4 acc1 = make_float4(0.f, 0.f, 0.f, 0.f);
    int j = s + sub;
    for (; j + 2 < e; j += 4) {            // edges j and j+2 concurrently
        unsigned int p0 = packed[j];
        unsigned int p1 = packed[j + 2];
        int c0 = (int)(p0 & 0x1FFFFu), t0 = (int)(p0 >> 17);
        int c1 = (int)(p1 & 0x1FFFFu), t1 = (int)(p1 >> 17);
        float n0 = dr * dinv[dbase + c0];
        float n1 = dr * dinv[dbase + c1];
        float4 xv0 = *reinterpret_cast<const float4*>(x + c0 * DIM + d);
        float4 rv0 = *reinterpret_cast<const float4*>(rel + t0 * DIM + d);
        float4 xv1 = *reinterpret_cast<const float4*>(x + c1 * DIM + d);
        float4 rv1 = *reinterpret_cast<const float4*>(rel + t1 * DIM + d);
        acc0.x += xv0.x * rv0.x * n0; acc0.y += xv0.y * rv0.y * n0;
        acc0.z += xv0.z * rv0.z * n0; acc0.w += xv0.w * rv0.w * n0;
        acc1.x += xv1.x * rv1.x * n1; acc1.y += xv1.y * rv1.y * n1;
        acc1.z += xv1.z * rv1.z * n1; acc1.w += xv1.w * rv1.w * n1;
    }
    if (j < e) {
        unsigned int p0 = packed[j];
        int c0 = (int)(p0 & 0x1FFFFu), t0 = (int)(p0 >> 17);
        float n0 = dr * dinv[dbase + c0];
        float4 xv0 = *reinterpret_cast<const float4*>(x + c0 * DIM + d);
        float4 rv0 = *reinterpret_cast<const float4*>(rel + t0 * DIM + d);
        acc0.x += xv0.x * rv0.x * n0; acc0.y += xv0.y * rv0.y * n0;
        acc0.z += xv0.z * rv0.z * n0; acc0.w += xv0.w * rv0.w * n0;
    }
    acc0.x += acc1.x; acc0.y += acc1.y; acc0.z += acc1.z; acc0.w += acc1.w;
    // combine sub-halves: lane l += lane l+32
    acc0.x += __shfl_down(acc0.x, 32, 64);
    acc0.y += __shfl_down(acc0.y, 32, 64);
    acc0.z += __shfl_down(acc0.z, 32, 64);
    acc0.w += __shfl_down(acc0.w, 32, 64);
    if (sub == 0 && slot < 25) {
        float* dst = (row < NE) ? (agg_in + (size_t)row * DIM)
                                : (agg_out + (size_t)(row - NE) * DIM);
        *reinterpret_cast<float4*>(dst + slot * 4) = acc0;
    }
}

// ============ atomic fallback (small-ws tier) ============
__global__ void k_agg_atomic(const int* __restrict__ ei, const int* __restrict__ et,
                             const float* __restrict__ x, const float* __restrict__ rel,
                             const float* __restrict__ dinv,
                             float* agg_in, float* agg_out, int E, int NE) {
    const int twoE = 2 * E;
    const int total = twoE * 25;
    int i = blockIdx.x * blockDim.x + threadIdx.x;
    int stride = gridDim.x * blockDim.x;
    for (; i < total; i += stride) {
        int e = i / 25;
        int d = (i - e * 25) * 4;
        int r = ei[e];
        int c = ei[twoE + e];
        int dbase = (e < E) ? 0 : NE;
        float norm = dinv[dbase + r] * dinv[dbase + c];
        if (norm != 0.f) {
            int t = et[e];
            float4 xv = *reinterpret_cast<const float4*>(x + c * DIM + d);
            float4 rv = *reinterpret_cast<const float4*>(rel + t * DIM + d);
            float* dst = ((e < E) ? agg_in : agg_out) + r * DIM + d;
            atomicAdd(dst + 0, xv.x * rv.x * norm);
            atomicAdd(dst + 1, xv.y * rv.y * norm);
            atomicAdd(dst + 2, xv.z * rv.z * norm);
            atomicAdd(dst + 3, xv.w * rv.w * norm);
        }
    }
}

// ============ W fragment pre-pack + rel matmul (fused, both weight-only) ============
#define WPREP_THREADS (3 * 4 * 7 * 64)
__global__ void k_wrel(const float* __restrict__ w_in, const float* __restrict__ w_out,
                       const float* __restrict__ w_loop, short* __restrict__ wfrag,
                       const float* __restrict__ rel, const float* __restrict__ w_rel,
                       float* __restrict__ out2, int nbW, int relTotal4) {
    int tid = threadIdx.x;
    if ((int)blockIdx.x < nbW) {
        int g = blockIdx.x * 256 + tid;
        if (g >= WPREP_THREADS) return;
        int lane = g & 63;
        int rest = g >> 6;
        int nt = rest % 7;
        int ks = (rest / 7) % 4;
        int src = rest / 28;
        const float* W = (src == 0) ? w_in : (src == 1) ? w_out : w_loop;
        int col = nt * 16 + (lane & 15);
        short8v frag;
#pragma unroll
        for (int j = 0; j < 8; ++j) {
            int k = ks * 32 + ((lane >> 4) << 3) + j;
            float v = (k < DIM && col < DIM) ? W[k * DIM + col] : 0.f;
            frag[j] = f2bf(v);
        }
        reinterpret_cast<short8v*>(wfrag)[g] = frag;
    } else {
        int i = (blockIdx.x - nbW) * 256 + tid;
        if (i >= relTotal4) return;
        int r = i / 25;
        int d = (i - r * 25) * 4;
        const float* a = rel + r * DIM;
        float4 acc = make_float4(0.f, 0.f, 0.f, 0.f);
#pragma unroll 4
        for (int k = 0; k < DIM; ++k) {
            float av = a[k];
            float4 w = *reinterpret_cast<const float4*>(w_rel + k * DIM + d);
            acc.x += av * w.x; acc.y += av * w.y; acc.z += av * w.z; acc.w += av * w.w;
        }
        *reinterpret_cast<float4*>(out2 + r * DIM + d) = acc;
    }
}

// ============ MFMA GEMM with fused column stats ============
__global__ __launch_bounds__(256) void k_gemm_mfma(
    const float* __restrict__ agg_in, const float* agg_out,
    const float* __restrict__ x, const float* __restrict__ loop_rel,
    const short* __restrict__ wfrag, float* out,
    float* __restrict__ colsum, float* __restrict__ colsumsq, int NE) {
    __shared__ float cs[112], cq[112];
    int tid = threadIdx.x;
    if (tid < 112) { cs[tid] = 0.f; cq[tid] = 0.f; }
    __syncthreads();

    int w = blockIdx.x * 4 + (tid >> 6);
    bool valid = (w * 16 < NE);
    int lane = tid & 63;
    int kg = lane >> 4;
    int cbase = lane & 15;

    f32x4v acc[7];
#pragma unroll
    for (int nt = 0; nt < 7; ++nt) acc[nt] = (f32x4v){0.f, 0.f, 0.f, 0.f};

    if (valid) {
        int row = w * 16 + cbase;
        for (int src = 0; src < 3; ++src) {
            const float* A = (src == 0) ? agg_in : (src == 1) ? agg_out : x;
            const float* Arow = A + (size_t)row * DIM;
#pragma unroll
            for (int ks = 0; ks < 4; ++ks) {
                int k0 = ks * 32 + kg * 8;
                short8v af = (short8v){0, 0, 0, 0, 0, 0, 0, 0};
                if (ks < 3) {
                    float4 lo = *reinterpret_cast<const float4*>(Arow + k0);
                    float4 hi = *reinterpret_cast<const float4*>(Arow + k0 + 4);
                    float v[8] = {lo.x, lo.y, lo.z, lo.w, hi.x, hi.y, hi.z, hi.w};
                    if (src == 2) {
                        float4 l0 = *reinterpret_cast<const float4*>(loop_rel + k0);
                        float4 l1 = *reinterpret_cast<const float4*>(loop_rel + k0 + 4);
                        v[0] *= l0.x; v[1] *= l0.y; v[2] *= l0.z; v[3] *= l0.w;
                        v[4] *= l1.x; v[5] *= l1.y; v[6] *= l1.z; v[7] *= l1.w;
                    }
#pragma unroll
                    for (int j = 0; j < 8; ++j) af[j] = f2bf(v[j]);
                } else if (kg == 0) {
                    float4 lo = *reinterpret_cast<const float4*>(Arow + 96);
                    float v[4] = {lo.x, lo.y, lo.z, lo.w};
                    if (src == 2) {
                        float4 l0 = *reinterpret_cast<const float4*>(loop_rel + 96);
                        v[0] *= l0.x; v[1] *= l0.y; v[2] *= l0.z; v[3] *= l0.w;
                    }
#pragma unroll
                    for (int j = 0; j < 4; ++j) af[j] = f2bf(v[j]);
                }
                int fb = ((src * 4 + ks) * 7) * 64 + lane;
#pragma unroll
                for (int nt = 0; nt < 7; ++nt) {
                    short8v bf = reinterpret_cast<const short8v*>(wfrag)[fb + nt * 64];
                    acc[nt] = __builtin_amdgcn_mfma_f32_16x16x32_bf16(af, bf, acc[nt], 0, 0, 0);
                }
            }
        }
        // epilogue: store + LDS stats
#pragma unroll
        for (int nt = 0; nt < 7; ++nt) {
            int col = nt * 16 + cbase;
            if (col < DIM) {
                float ps = acc[nt][0] + acc[nt][1] + acc[nt][2] + acc[nt][3];
                float pq = acc[nt][0] * acc[nt][0] + acc[nt][1] * acc[nt][1]
                         + acc[nt][2] * acc[nt][2] + acc[nt][3] * acc[nt][3];
#pragma unroll
                for (int r = 0; r < 4; ++r) {
                    int orow = w * 16 + kg * 4 + r;
                    out[(size_t)orow * DIM + col] = acc[nt][r];
                }
                atomicAdd(&cs[col], ps);
                atomicAdd(&cq[col], pq);
            }
        }
    }
    __syncthreads();
    if (tid < DIM) {
        atomicAdd(&colsum[tid], cs[tid]);
        atomicAdd(&colsumsq[tid], cq[tid]);
    }
}

// ============ BN + tanh with inline finalize ============
__global__ void k_bn_tanh4(float* __restrict__ v, const float* __restrict__ colsum,
                           const float* __restrict__ colsumsq,
                           const float* __restrict__ gamma, const float* __restrict__ beta,
                           float invN, int total4) {
    int i = blockIdx.x * blockDim.x + threadIdx.x;
    if (i >= total4) return;
    int d = (i % 25) * 4;
    float4 val = reinterpret_cast<float4*>(v)[i];
    float4 sm = *reinterpret_cast<const float4*>(colsum + d);
    float4 sq = *reinterpret_cast<const float4*>(colsumsq + d);
    float4 g  = *reinterpret_cast<const float4*>(gamma + d);
    float4 b  = *reinterpret_cast<const float4*>(beta + d);
#define BNT(c) { float mu = sm.c * invN; float var = sq.c * invN - mu * mu;            \
                 if (var < 0.f) var = 0.f;                                             \
                 float s = rsqrtf(var * (1.0f / 9.0f) + BN_EPS) * (1.0f / 3.0f) * g.c; \
                 float t = b.c - mu * s;                                               \
                 val.c = tanhf(val.c * s + t); }
    BNT(x) BNT(y) BNT(z) BNT(w)
#undef BNT
    reinterpret_cast<float4*>(v)[i] = val;
}

extern "C" void kernel_launch(void* const* d_in, const int* in_sizes, int n_in,
                              void* d_out, int out_size, void* d_ws, size_t ws_size,
                              hipStream_t stream) {
    const float* x        = (const float*)d_in[0];
    const int*   ei       = (const int*)d_in[1];
    const int*   et       = (const int*)d_in[2];
    const float* rel      = (const float*)d_in[3];
    const float* w_in     = (const float*)d_in[4];
    const float* w_out    = (const float*)d_in[5];
    const float* w_loop   = (const float*)d_in[6];
    const float* w_rel    = (const float*)d_in[7];
    const float* loop_rel = (const float*)d_in[8];
    const float* gamma    = (const float*)d_in[10];
    const float* beta     = (const float*)d_in[11];

    const int NE = in_sizes[0] / DIM;     // 50000
    const int E  = in_sizes[2] / 2;       // 500000

    float* out  = (float*)d_out;
    float* out2 = out + (size_t)NE * DIM;
    const int relRows = in_sizes[3] / DIM;

    const int B = 256;
    const size_t aggElems = (size_t)NE * DIM;
    const size_t twoNE = 2 * (size_t)NE;
    const int n = (int)twoNE;
    const int nb = (n + 1023) / 1024;
    const int WFRAG_SHORTS = 3 * 4 * 7 * 64 * 8;
    const int WFRAG_INTS = WFRAG_SHORTS / 2;

    // ws layout (ints):
    // hist[2NE] | colsum[128] colsumsq[128] | blocksum[128] blockoff[128]
    // | dinv[2NE] | base[2NE+16] | cursor[2NE] | wfrag[21504] | packed[2E] | agg_in[NE*DIM]
    int* wsI = (int*)d_ws;
    int*   hist     = wsI;
    float* colsum   = (float*)(hist + twoNE);
    float* colsumsq = colsum + 128;
    int*   blocksum = (int*)(colsumsq + 128);
    int*   blockoff = blocksum + 128;

    const size_t needSorted = (twoNE + 256 + 256 + twoNE + (twoNE + 16) + twoNE
                               + WFRAG_INTS + 2 * (size_t)E + aggElems) * 4;

    const int relTotal4 = relRows * (DIM / 4);
    const int nbW = (WPREP_THREADS + 255) / 256;
    const int nbR = (relTotal4 + 255) / 256;

    if (ws_size >= needSorted && NE <= 131072) {
        float* dinv   = (float*)(blockoff + 128);
        int*   base   = (int*)(dinv + twoNE);
        int*   cursor = base + twoNE + 16;
        short* wfrag  = (short*)(cursor + twoNE);
        unsigned int* packed = (unsigned int*)(cursor + twoNE + WFRAG_INTS);
        float* agg_in = (float*)(packed + 2 * (size_t)E);
        float* agg_out = out;   // alias: safe, each gemm wave reads only its own rows

        hipMemsetAsync(hist, 0, (twoNE + 256) * 4, stream);

        k_hist<<<1024, B, 0, stream>>>(ei, hist, E, NE);
        k_scanA<<<nb, B, 0, stream>>>(hist, base, blocksum, dinv, n);
        k_scanB<<<1, 256, 0, stream>>>(blocksum, blockoff, nb);
        k_scanC<<<nb, B, 0, stream>>>(base, cursor, blockoff, n, 2 * E);
        k_scatter<<<1024, B, 0, stream>>>(ei, et, cursor, packed, E, NE);
        k_wrel<<<nbW + nbR, B, 0, stream>>>(w_in, w_out, w_loop, wfrag,
                                            rel, w_rel, out2, nbW, relTotal4);
        k_agg2<<<(n + 3) / 4, B, 0, stream>>>(packed, base, x, rel, dinv,
                                              agg_in, agg_out, NE);
        k_gemm_mfma<<<(NE / 16 + 3) / 4, B, 0, stream>>>(agg_in, agg_out, x, loop_rel,
                                                         wfrag, out, colsum, colsumsq, NE);
    } else {
        // atomic fallback
        float* dinv   = (float*)(blockoff + 128);
        float* agg_in = dinv + twoNE;
        short* wfrag  = (short*)(agg_in + aggElems);
        float* agg_out = out;

        hipMemsetAsync(hist, 0, (twoNE + 256) * 4, stream);
        hipMemsetAsync(agg_in, 0, aggElems * 4, stream);
        hipMemsetAsync(out, 0, aggElems * 4, stream);

        k_hist<<<1024, B, 0, stream>>>(ei, hist, E, NE);
        k_dinv<<<(n + B - 1) / B, B, 0, stream>>>(hist, dinv, n);
        k_wrel<<<nbW + nbR, B, 0, stream>>>(w_in, w_out, w_loop, wfrag,
                                            rel, w_rel, out2, nbW, relTotal4);
        k_agg_atomic<<<8192, B, 0, stream>>>(ei, et, x, rel, dinv, agg_in, agg_out, E, NE);
        k_gemm_mfma<<<(NE / 16 + 3) / 4, B, 0, stream>>>(agg_in, agg_out, x, loop_rel,
                                                         wfrag, out, colsum, colsumsq, NE);
    }

    int total4 = NE * (DIM / 4);
    k_bn_tanh4<<<(total4 + B - 1) / B, B, 0, stream>>>(out, colsum, colsumsq,
                                                       gamma, beta, 1.0f / NE, total4);
}